// Round 1
// baseline (55886.456 us; speedup 1.0000x reference)
//
#include <hip/hip_runtime.h>

#define SEQ_T 1024
#define NB    128
#define HID   1024
#define EMB   512
#define VOC   512

typedef _Float16 f16;
typedef _Float16 half8 __attribute__((ext_vector_type(8)));
typedef float floatx4 __attribute__((ext_vector_type(4)));

__device__ __forceinline__ float tanh_fast(float x) {
  float e = __expf(2.0f * x);
  return 1.0f - 2.0f / (e + 1.0f);
}

__global__ void cvt_f32_f16(const float* __restrict__ src, f16* __restrict__ dst, int n) {
  int i = blockIdx.x * 256 + threadIdx.x;
  if (i < n) dst[i] = (f16)src[i];
}

// X0[(t*NB+b)][j] = sum_k emb[ids[b][t]][k] * wxh0[j][k] + b_h0[j]   (store f16)
// grid: 2048 m-tiles x 16 n-tiles, 64x64 tile per WG, 4 waves of 32x32
__global__ __launch_bounds__(256) void phaseA(
    const int* __restrict__ ids, const f16* __restrict__ embh,
    const f16* __restrict__ wxh0h, const float* __restrict__ bh0,
    f16* __restrict__ X0)
{
  int bx = blockIdx.x;
  int mt = bx >> 4, nt = bx & 15;
  int wave = threadIdx.x >> 6, lane = threadIdx.x & 63;
  int m0 = mt * 64 + (wave & 1) * 32;
  int n0 = nt * 64 + (wave >> 1) * 32;
  int l15 = lane & 15, q = lane >> 4;

  int mA = m0 + l15, mB = mA + 16;
  const f16* a0p = embh + (size_t)ids[(mA & 127) * SEQ_T + (mA >> 7)] * EMB + q * 8;
  const f16* a1p = embh + (size_t)ids[(mB & 127) * SEQ_T + (mB >> 7)] * EMB + q * 8;
  const f16* b0p = wxh0h + (size_t)(n0 + l15) * EMB + q * 8;
  const f16* b1p = wxh0h + (size_t)(n0 + 16 + l15) * EMB + q * 8;

  floatx4 acc[2][2] = {};
  for (int k = 0; k < EMB; k += 32) {
    half8 a0 = *(const half8*)(a0p + k);
    half8 a1 = *(const half8*)(a1p + k);
    half8 b0 = *(const half8*)(b0p + k);
    half8 b1 = *(const half8*)(b1p + k);
    acc[0][0] = __builtin_amdgcn_mfma_f32_16x16x32_f16(a0, b0, acc[0][0], 0, 0, 0);
    acc[0][1] = __builtin_amdgcn_mfma_f32_16x16x32_f16(a0, b1, acc[0][1], 0, 0, 0);
    acc[1][0] = __builtin_amdgcn_mfma_f32_16x16x32_f16(a1, b0, acc[1][0], 0, 0, 0);
    acc[1][1] = __builtin_amdgcn_mfma_f32_16x16x32_f16(a1, b1, acc[1][1], 0, 0, 0);
  }
  for (int i = 0; i < 2; i++)
    for (int j = 0; j < 2; j++) {
      int col = n0 + j * 16 + l15;
      float bias = bh0[col];
      for (int e = 0; e < 4; e++) {
        int row = m0 + i * 16 + q * 4 + e;
        X0[(size_t)row * HID + col] = (f16)(acc[i][j][e] + bias);
      }
    }
}

// h0new[b][j] = tanh(X0t[b][j] + sum_k h0old[b][k]*whh0[j][k])
// grid: 2 m-tiles x 16 n-tiles = 32 WGs
__global__ __launch_bounds__(256) void stepA(
    const f16* __restrict__ h0old, const f16* __restrict__ whh0h,
    const f16* __restrict__ X0t, f16* __restrict__ h0new)
{
  int bx = blockIdx.x;
  int mt = bx & 1, nt = bx >> 1;
  int wave = threadIdx.x >> 6, lane = threadIdx.x & 63;
  int m0 = mt * 64 + (wave & 1) * 32;
  int n0 = nt * 64 + (wave >> 1) * 32;
  int l15 = lane & 15, q = lane >> 4;

  const f16* a0p = h0old + (size_t)(m0 + l15) * HID + q * 8;
  const f16* a1p = h0old + (size_t)(m0 + 16 + l15) * HID + q * 8;
  const f16* b0p = whh0h + (size_t)(n0 + l15) * HID + q * 8;
  const f16* b1p = whh0h + (size_t)(n0 + 16 + l15) * HID + q * 8;

  floatx4 acc[2][2] = {};
  for (int k = 0; k < HID; k += 32) {
    half8 a0 = *(const half8*)(a0p + k);
    half8 a1 = *(const half8*)(a1p + k);
    half8 b0 = *(const half8*)(b0p + k);
    half8 b1 = *(const half8*)(b1p + k);
    acc[0][0] = __builtin_amdgcn_mfma_f32_16x16x32_f16(a0, b0, acc[0][0], 0, 0, 0);
    acc[0][1] = __builtin_amdgcn_mfma_f32_16x16x32_f16(a0, b1, acc[0][1], 0, 0, 0);
    acc[1][0] = __builtin_amdgcn_mfma_f32_16x16x32_f16(a1, b0, acc[1][0], 0, 0, 0);
    acc[1][1] = __builtin_amdgcn_mfma_f32_16x16x32_f16(a1, b1, acc[1][1], 0, 0, 0);
  }
  for (int i = 0; i < 2; i++)
    for (int j = 0; j < 2; j++) {
      int col = n0 + j * 16 + l15;
      for (int e = 0; e < 4; e++) {
        int row = m0 + i * 16 + q * 4 + e;
        float v = acc[i][j][e] + (float)X0t[(size_t)row * HID + col];
        h0new[(size_t)row * HID + col] = (f16)tanh_fast(v);
      }
    }
}

// h1new[b][j] = tanh(bh1[j] + sum_k h0new[b][k]*wxh1[j][k] + sum_k h1old[b][k]*whh1[j][k])
// also store to H1t (for final logits GEMM)
__global__ __launch_bounds__(256) void stepB(
    const f16* __restrict__ h0new, const f16* __restrict__ h1old,
    const f16* __restrict__ wxh1h, const f16* __restrict__ whh1h,
    const float* __restrict__ bh1,
    f16* __restrict__ h1new, f16* __restrict__ H1t)
{
  int bx = blockIdx.x;
  int mt = bx & 1, nt = bx >> 1;
  int wave = threadIdx.x >> 6, lane = threadIdx.x & 63;
  int m0 = mt * 64 + (wave & 1) * 32;
  int n0 = nt * 64 + (wave >> 1) * 32;
  int l15 = lane & 15, q = lane >> 4;

  size_t ra0 = (size_t)(m0 + l15) * HID + q * 8;
  size_t ra1 = (size_t)(m0 + 16 + l15) * HID + q * 8;
  size_t rb0 = (size_t)(n0 + l15) * HID + q * 8;
  size_t rb1 = (size_t)(n0 + 16 + l15) * HID + q * 8;

  floatx4 acc[2][2] = {};
  for (int k = 0; k < HID; k += 32) {
    half8 a0 = *(const half8*)(h0new + ra0 + k);
    half8 a1 = *(const half8*)(h0new + ra1 + k);
    half8 b0 = *(const half8*)(wxh1h + rb0 + k);
    half8 b1 = *(const half8*)(wxh1h + rb1 + k);
    acc[0][0] = __builtin_amdgcn_mfma_f32_16x16x32_f16(a0, b0, acc[0][0], 0, 0, 0);
    acc[0][1] = __builtin_amdgcn_mfma_f32_16x16x32_f16(a0, b1, acc[0][1], 0, 0, 0);
    acc[1][0] = __builtin_amdgcn_mfma_f32_16x16x32_f16(a1, b0, acc[1][0], 0, 0, 0);
    acc[1][1] = __builtin_amdgcn_mfma_f32_16x16x32_f16(a1, b1, acc[1][1], 0, 0, 0);
  }
  for (int k = 0; k < HID; k += 32) {
    half8 a0 = *(const half8*)(h1old + ra0 + k);
    half8 a1 = *(const half8*)(h1old + ra1 + k);
    half8 b0 = *(const half8*)(whh1h + rb0 + k);
    half8 b1 = *(const half8*)(whh1h + rb1 + k);
    acc[0][0] = __builtin_amdgcn_mfma_f32_16x16x32_f16(a0, b0, acc[0][0], 0, 0, 0);
    acc[0][1] = __builtin_amdgcn_mfma_f32_16x16x32_f16(a0, b1, acc[0][1], 0, 0, 0);
    acc[1][0] = __builtin_amdgcn_mfma_f32_16x16x32_f16(a1, b0, acc[1][0], 0, 0, 0);
    acc[1][1] = __builtin_amdgcn_mfma_f32_16x16x32_f16(a1, b1, acc[1][1], 0, 0, 0);
  }
  for (int i = 0; i < 2; i++)
    for (int j = 0; j < 2; j++) {
      int col = n0 + j * 16 + l15;
      float bias = bh1[col];
      for (int e = 0; e < 4; e++) {
        int row = m0 + i * 16 + q * 4 + e;
        f16 v = (f16)tanh_fast(acc[i][j][e] + bias);
        h1new[(size_t)row * HID + col] = v;
        H1t[(size_t)row * HID + col] = v;
      }
    }
}

// logits[b][t][v] = sum_k H1[(t*NB+b)][k]*why[v][k] + by[v]   (fp32 out)
// grid: 2048 m-tiles x 8 n-tiles
__global__ __launch_bounds__(256) void logitsK(
    const f16* __restrict__ H1, const f16* __restrict__ whyh,
    const float* __restrict__ by, float* __restrict__ out)
{
  int bx = blockIdx.x;
  int mt = bx >> 3, nt = bx & 7;
  int wave = threadIdx.x >> 6, lane = threadIdx.x & 63;
  int m0 = mt * 64 + (wave & 1) * 32;
  int n0 = nt * 64 + (wave >> 1) * 32;
  int l15 = lane & 15, q = lane >> 4;

  const f16* a0p = H1 + (size_t)(m0 + l15) * HID + q * 8;
  const f16* a1p = H1 + (size_t)(m0 + 16 + l15) * HID + q * 8;
  const f16* b0p = whyh + (size_t)(n0 + l15) * HID + q * 8;
  const f16* b1p = whyh + (size_t)(n0 + 16 + l15) * HID + q * 8;

  floatx4 acc[2][2] = {};
  for (int k = 0; k < HID; k += 32) {
    half8 a0 = *(const half8*)(a0p + k);
    half8 a1 = *(const half8*)(a1p + k);
    half8 b0 = *(const half8*)(b0p + k);
    half8 b1 = *(const half8*)(b1p + k);
    acc[0][0] = __builtin_amdgcn_mfma_f32_16x16x32_f16(a0, b0, acc[0][0], 0, 0, 0);
    acc[0][1] = __builtin_amdgcn_mfma_f32_16x16x32_f16(a0, b1, acc[0][1], 0, 0, 0);
    acc[1][0] = __builtin_amdgcn_mfma_f32_16x16x32_f16(a1, b0, acc[1][0], 0, 0, 0);
    acc[1][1] = __builtin_amdgcn_mfma_f32_16x16x32_f16(a1, b1, acc[1][1], 0, 0, 0);
  }
  for (int i = 0; i < 2; i++)
    for (int j = 0; j < 2; j++) {
      int col = n0 + j * 16 + l15;
      float bias = by[col];
      for (int e = 0; e < 4; e++) {
        int row = m0 + i * 16 + q * 4 + e;   // row = t*128 + b
        int t = row >> 7, b = row & 127;
        out[((size_t)b * SEQ_T + t) * VOC + col] = acc[i][j][e] + bias;
      }
    }
}

__global__ void finals(const f16* __restrict__ h0, const f16* __restrict__ h1,
                       float* __restrict__ out) {
  int i = blockIdx.x * 256 + threadIdx.x;  // 131072 threads
  out[(size_t)67108864 + i] = (float)h0[i];
  out[(size_t)67108864 + 131072 + i] = (float)h1[i];
}

extern "C" void kernel_launch(void* const* d_in, const int* in_sizes, int n_in,
                              void* d_out, int out_size, void* d_ws, size_t ws_size,
                              hipStream_t stream) {
  const int*   ids  = (const int*)d_in[0];
  const float* emb  = (const float*)d_in[1];
  const float* wxh0 = (const float*)d_in[2];
  const float* whh0 = (const float*)d_in[3];
  const float* bh0  = (const float*)d_in[4];
  const float* wxh1 = (const float*)d_in[5];
  const float* whh1 = (const float*)d_in[6];
  const float* bh1  = (const float*)d_in[7];
  const float* why  = (const float*)d_in[8];
  const float* by   = (const float*)d_in[9];
  float* out = (float*)d_out;

  char* ws = (char*)d_ws;
  f16* embh  = (f16*)(ws + 0);          // 512*512*2      = 524288
  f16* wxh0h = (f16*)(ws + 524288);     // 1024*512*2     = 1048576
  f16* whh0h = (f16*)(ws + 1572864);    // 1024*1024*2    = 2097152
  f16* wxh1h = (f16*)(ws + 3670016);    // 2097152
  f16* whh1h = (f16*)(ws + 5767168);    // 2097152
  f16* whyh  = (f16*)(ws + 7864320);    // 512*1024*2     = 1048576
  f16* h0buf = (f16*)(ws + 8912896);    // 2 x 131072 f16 = 524288
  f16* h1buf = (f16*)(ws + 9437184);    // 524288
  f16* X0    = (f16*)(ws + 10485760);   // 131072*1024*2  = 268435456
  f16* H1    = (f16*)(ws + 278921216);  // 268435456  (total ~547 MB)

  cvt_f32_f16<<<1024, 256, 0, stream>>>(emb,  embh,  262144);
  cvt_f32_f16<<<2048, 256, 0, stream>>>(wxh0, wxh0h, 524288);
  cvt_f32_f16<<<4096, 256, 0, stream>>>(whh0, whh0h, 1048576);
  cvt_f32_f16<<<4096, 256, 0, stream>>>(wxh1, wxh1h, 1048576);
  cvt_f32_f16<<<4096, 256, 0, stream>>>(whh1, whh1h, 1048576);
  cvt_f32_f16<<<2048, 256, 0, stream>>>(why,  whyh,  524288);
  hipMemsetAsync(h0buf, 0, 1048576, stream);  // zeroes h0buf+h1buf (adjacent)

  phaseA<<<32768, 256, 0, stream>>>(ids, embh, wxh0h, bh0, X0);

  for (int t = 0; t < SEQ_T; ++t) {
    int cur = t & 1;
    f16* h0o = h0buf + (size_t)cur * 131072;
    f16* h0n = h0buf + (size_t)(cur ^ 1) * 131072;
    f16* h1o = h1buf + (size_t)cur * 131072;
    f16* h1n = h1buf + (size_t)(cur ^ 1) * 131072;
    stepA<<<32, 256, 0, stream>>>(h0o, whh0h, X0 + (size_t)t * 131072, h0n);
    stepB<<<32, 256, 0, stream>>>(h0n, h1o, wxh1h, whh1h, bh1, h1n,
                                  H1 + (size_t)t * 131072);
  }

  logitsK<<<16384, 256, 0, stream>>>(H1, whyh, by, out);
  finals<<<512, 256, 0, stream>>>(h0buf, h1buf, out);
}

// Round 3
// 26064.944 us; speedup vs baseline: 2.1441x; 2.1441x over previous
//
#include <hip/hip_runtime.h>

#define SEQ_T 1024
#define HID   1024
#define EMB   512
#define VOC   512

typedef _Float16 f16;
typedef _Float16 half8 __attribute__((ext_vector_type(8)));
typedef float floatx4 __attribute__((ext_vector_type(4)));

__device__ __forceinline__ float tanh_fast(float x) {
  float e = __expf(2.0f * x);
  return 1.0f - 2.0f / (e + 1.0f);
}

__global__ void cvt_f32_f16(const float* __restrict__ src, f16* __restrict__ dst, int n) {
  int i = blockIdx.x * 256 + threadIdx.x;
  if (i < n) dst[i] = (f16)src[i];
}

// X0[(t*128+b)][j] = sum_k emb[ids[b][t]][k] * wxh0[j][k] + b_h0[j]   (store f16)
__global__ __launch_bounds__(256) void phaseA(
    const int* __restrict__ ids, const f16* __restrict__ embh,
    const f16* __restrict__ wxh0h, const float* __restrict__ bh0,
    f16* __restrict__ X0)
{
  int bx = blockIdx.x;
  int mt = bx >> 4, nt = bx & 15;
  int wave = threadIdx.x >> 6, lane = threadIdx.x & 63;
  int m0 = mt * 64 + (wave & 1) * 32;
  int n0 = nt * 64 + (wave >> 1) * 32;
  int l15 = lane & 15, q = lane >> 4;

  int mA = m0 + l15, mB = mA + 16;
  const f16* a0p = embh + (size_t)ids[(mA & 127) * SEQ_T + (mA >> 7)] * EMB + q * 8;
  const f16* a1p = embh + (size_t)ids[(mB & 127) * SEQ_T + (mB >> 7)] * EMB + q * 8;
  const f16* b0p = wxh0h + (size_t)(n0 + l15) * EMB + q * 8;
  const f16* b1p = wxh0h + (size_t)(n0 + 16 + l15) * EMB + q * 8;

  floatx4 acc[2][2] = {};
  for (int k = 0; k < EMB; k += 32) {
    half8 a0 = *(const half8*)(a0p + k);
    half8 a1 = *(const half8*)(a1p + k);
    half8 b0 = *(const half8*)(b0p + k);
    half8 b1 = *(const half8*)(b1p + k);
    acc[0][0] = __builtin_amdgcn_mfma_f32_16x16x32_f16(a0, b0, acc[0][0], 0, 0, 0);
    acc[0][1] = __builtin_amdgcn_mfma_f32_16x16x32_f16(a0, b1, acc[0][1], 0, 0, 0);
    acc[1][0] = __builtin_amdgcn_mfma_f32_16x16x32_f16(a1, b0, acc[1][0], 0, 0, 0);
    acc[1][1] = __builtin_amdgcn_mfma_f32_16x16x32_f16(a1, b1, acc[1][1], 0, 0, 0);
  }
  for (int i = 0; i < 2; i++)
    for (int j = 0; j < 2; j++) {
      int col = n0 + j * 16 + l15;
      float bias = bh0[col];
      for (int e = 0; e < 4; e++) {
        int row = m0 + i * 16 + q * 4 + e;
        X0[(size_t)row * HID + col] = (f16)(acc[i][j][e] + bias);
      }
    }
}

__device__ __forceinline__ void spin_ge(unsigned* p, unsigned tgt) {
  while (__hip_atomic_load(p, __ATOMIC_RELAXED, __HIP_MEMORY_SCOPE_AGENT) < tgt)
    __builtin_amdgcn_s_sleep(1);
}

// Persistent recurrence kernel (regular launch, 256 WGs co-resident at 1 WG/CU).
// WGs 0..127 = A-phase, 128..255 = B-phase.
// A-WG(r,c): h0new[16 rows r][64 cols c] = tanh(X0[t] + h0old . Whh0^T)
// B-WG(r,c): h1new[16 rows r][64 cols c] = tanh(b1 + h0new . Wxh1^T + h1old . Whh1^T)
// Weights held in registers as MFMA B-frags. Sync via per-row-group counters
// with explicit agent-scope fences (cross-XCD L2 writeback/invalidate).
__global__ __launch_bounds__(256, 1) void rnn_persist(
    const float* __restrict__ whh0, const float* __restrict__ wxh1,
    const float* __restrict__ whh1, const float* __restrict__ bh1,
    const f16* __restrict__ X0, f16* __restrict__ h0buf, f16* __restrict__ h1buf,
    f16* __restrict__ H1, unsigned* __restrict__ cnt)
{
  const int wg = blockIdx.x;
  const bool isB = wg >= 128;
  const int id = isB ? (wg - 128) : wg;
  const int r = id >> 4;           // row-block 0..7 (16 batch rows each)
  const int c = id & 15;           // col-block 0..15 (64 cols each)
  const int wave = threadIdx.x >> 6;
  const int lane = threadIdx.x & 63;
  const int l15 = lane & 15, q = lane >> 4;
  const int r0 = r * 16;
  const int n0 = c * 64 + wave * 16;
  const int col = n0 + l15;

  unsigned* cA = cnt + r * 64;          // cacheline-separated counters
  unsigned* cB = cnt + 512 + r * 64;

  if (!isB) {
    // ---- A phase: weights = Whh0[col][k], k=0..1023 -> 32 frags ----
    half8 wa[32];
    {
      const float* wr = whh0 + (size_t)col * HID + q * 8;
      #pragma unroll
      for (int i = 0; i < 32; i++) {
        const float* p = wr + i * 32;
        #pragma unroll
        for (int j = 0; j < 8; j++) wa[i][j] = (f16)p[j];
      }
    }
    for (int t = 0; t < SEQ_T; t++) {
      const f16* h0prev = h0buf + (size_t)(t & 1) * 131072;
      f16* h0next = h0buf + (size_t)((t + 1) & 1) * 131072;
      if (threadIdx.x == 0) {
        spin_ge(cA, 16u * t);                    // A(t-1) row r complete
        if (t >= 2) spin_ge(cB, 16u * (t - 1));  // B(t-2) done reading buffer
        __threadfence();                         // agent acquire: inv L1/L2
      }
      __syncthreads();
      floatx4 acc = {};
      const f16* ap = h0prev + (size_t)(r0 + l15) * HID + q * 8;
      #pragma unroll
      for (int i = 0; i < 32; i++) {
        half8 a = *(const half8*)(ap + i * 32);
        acc = __builtin_amdgcn_mfma_f32_16x16x32_f16(a, wa[i], acc, 0, 0, 0);
      }
      const f16* x0t = X0 + (size_t)t * 131072;
      #pragma unroll
      for (int e = 0; e < 4; e++) {
        int row = r0 + q * 4 + e;
        float v = acc[e] + (float)x0t[(size_t)row * HID + col];
        h0next[(size_t)row * HID + col] = (f16)tanh_fast(v);
      }
      __syncthreads();   // all waves' stores drained (vmcnt) before release
      if (threadIdx.x == 0) {
        __threadfence();                         // agent release: wb L2
        __hip_atomic_fetch_add(cA, 1u, __ATOMIC_RELAXED, __HIP_MEMORY_SCOPE_AGENT);
      }
    }
  } else {
    // ---- B phase: weights = [Wxh1 | Whh1][col][k] -> 64 frags ----
    half8 wb[64];
    {
      const float* wr1 = wxh1 + (size_t)col * HID + q * 8;
      const float* wr2 = whh1 + (size_t)col * HID + q * 8;
      #pragma unroll
      for (int i = 0; i < 32; i++) {
        const float* p = wr1 + i * 32;
        #pragma unroll
        for (int j = 0; j < 8; j++) wb[i][j] = (f16)p[j];
      }
      #pragma unroll
      for (int i = 0; i < 32; i++) {
        const float* p = wr2 + i * 32;
        #pragma unroll
        for (int j = 0; j < 8; j++) wb[32 + i][j] = (f16)p[j];
      }
    }
    const float bias = bh1[col];
    for (int t = 0; t < SEQ_T; t++) {
      const f16* h1old = h1buf + (size_t)(t & 1) * 131072;
      f16* h1new = h1buf + (size_t)((t + 1) & 1) * 131072;
      const f16* h0cur = h0buf + (size_t)((t + 1) & 1) * 131072;  // written by A(t)
      if (threadIdx.x == 0) {
        spin_ge(cA, 16u * (t + 1));   // A(t) row r complete
        spin_ge(cB, 16u * t);         // B(t-1) row r complete
        __threadfence();              // agent acquire: inv L1/L2
      }
      __syncthreads();
      floatx4 acc = {};
      const f16* ap0 = h0cur + (size_t)(r0 + l15) * HID + q * 8;
      #pragma unroll
      for (int i = 0; i < 32; i++) {
        half8 a = *(const half8*)(ap0 + i * 32);
        acc = __builtin_amdgcn_mfma_f32_16x16x32_f16(a, wb[i], acc, 0, 0, 0);
      }
      const f16* ap1 = h1old + (size_t)(r0 + l15) * HID + q * 8;
      #pragma unroll
      for (int i = 0; i < 32; i++) {
        half8 a = *(const half8*)(ap1 + i * 32);
        acc = __builtin_amdgcn_mfma_f32_16x16x32_f16(a, wb[32 + i], acc, 0, 0, 0);
      }
      f16* h1t = H1 + (size_t)t * 131072;
      #pragma unroll
      for (int e = 0; e < 4; e++) {
        int row = r0 + q * 4 + e;
        f16 v = (f16)tanh_fast(acc[e] + bias);
        h1new[(size_t)row * HID + col] = v;
        h1t[(size_t)row * HID + col] = v;
      }
      __syncthreads();
      if (threadIdx.x == 0) {
        __threadfence();              // agent release: wb L2
        __hip_atomic_fetch_add(cB, 1u, __ATOMIC_RELAXED, __HIP_MEMORY_SCOPE_AGENT);
      }
    }
  }
}

// logits[b][t][v] = sum_k H1[(t*128+b)][k]*why[v][k] + by[v]   (fp32 out)
__global__ __launch_bounds__(256) void logitsK(
    const f16* __restrict__ H1, const f16* __restrict__ whyh,
    const float* __restrict__ by, float* __restrict__ out)
{
  int bx = blockIdx.x;
  int mt = bx >> 3, nt = bx & 7;
  int wave = threadIdx.x >> 6, lane = threadIdx.x & 63;
  int m0 = mt * 64 + (wave & 1) * 32;
  int n0 = nt * 64 + (wave >> 1) * 32;
  int l15 = lane & 15, q = lane >> 4;

  const f16* a0p = H1 + (size_t)(m0 + l15) * HID + q * 8;
  const f16* a1p = H1 + (size_t)(m0 + 16 + l15) * HID + q * 8;
  const f16* b0p = whyh + (size_t)(n0 + l15) * HID + q * 8;
  const f16* b1p = whyh + (size_t)(n0 + 16 + l15) * HID + q * 8;

  floatx4 acc[2][2] = {};
  for (int k = 0; k < HID; k += 32) {
    half8 a0 = *(const half8*)(a0p + k);
    half8 a1 = *(const half8*)(a1p + k);
    half8 b0 = *(const half8*)(b0p + k);
    half8 b1 = *(const half8*)(b1p + k);
    acc[0][0] = __builtin_amdgcn_mfma_f32_16x16x32_f16(a0, b0, acc[0][0], 0, 0, 0);
    acc[0][1] = __builtin_amdgcn_mfma_f32_16x16x32_f16(a0, b1, acc[0][1], 0, 0, 0);
    acc[1][0] = __builtin_amdgcn_mfma_f32_16x16x32_f16(a1, b0, acc[1][0], 0, 0, 0);
    acc[1][1] = __builtin_amdgcn_mfma_f32_16x16x32_f16(a1, b1, acc[1][1], 0, 0, 0);
  }
  for (int i = 0; i < 2; i++)
    for (int j = 0; j < 2; j++) {
      int col = n0 + j * 16 + l15;
      float bias = by[col];
      for (int e = 0; e < 4; e++) {
        int row = m0 + i * 16 + q * 4 + e;   // row = t*128 + b
        int t = row >> 7, b = row & 127;
        out[((size_t)b * SEQ_T + t) * VOC + col] = acc[i][j][e] + bias;
      }
    }
}

__global__ void finals(const f16* __restrict__ h0, const f16* __restrict__ h1,
                       float* __restrict__ out) {
  int i = blockIdx.x * 256 + threadIdx.x;  // 131072 threads
  out[(size_t)67108864 + i] = (float)h0[i];
  out[(size_t)67108864 + 131072 + i] = (float)h1[i];
}

extern "C" void kernel_launch(void* const* d_in, const int* in_sizes, int n_in,
                              void* d_out, int out_size, void* d_ws, size_t ws_size,
                              hipStream_t stream) {
  const int*   ids  = (const int*)d_in[0];
  const float* emb  = (const float*)d_in[1];
  const float* wxh0 = (const float*)d_in[2];
  const float* whh0 = (const float*)d_in[3];
  const float* bh0  = (const float*)d_in[4];
  const float* wxh1 = (const float*)d_in[5];
  const float* whh1 = (const float*)d_in[6];
  const float* bh1  = (const float*)d_in[7];
  const float* why  = (const float*)d_in[8];
  const float* by   = (const float*)d_in[9];
  float* out = (float*)d_out;

  char* ws = (char*)d_ws;
  f16* embh   = (f16*)(ws + 0);           // 512*512*2   = 524288
  f16* wxh0h  = (f16*)(ws + 524288);      // 1024*512*2  = 1048576
  f16* whyh   = (f16*)(ws + 1572864);     // 512*1024*2  = 1048576
  f16* h0buf  = (f16*)(ws + 2621440);     // 2 x 262144B = 524288
  f16* h1buf  = (f16*)(ws + 3145728);     // 524288
  unsigned* cnt = (unsigned*)(ws + 3670016);  // 4096
  f16* X0     = (f16*)(ws + 4194304);     // 268435456
  f16* H1     = (f16*)(ws + 272629760);   // 268435456   total ~528 MB

  cvt_f32_f16<<<1024, 256, 0, stream>>>(emb,  embh,  262144);
  cvt_f32_f16<<<2048, 256, 0, stream>>>(wxh0, wxh0h, 524288);
  cvt_f32_f16<<<2048, 256, 0, stream>>>(why,  whyh,  524288);
  hipMemsetAsync(ws + 2621440, 0, 1052672, stream);  // h0buf + h1buf + cnt

  phaseA<<<32768, 256, 0, stream>>>(ids, embh, wxh0h, bh0, X0);

  rnn_persist<<<256, 256, 0, stream>>>(whh0, wxh1, whh1, bh1,
                                       X0, h0buf, h1buf, H1, cnt);

  logitsK<<<16384, 256, 0, stream>>>(H1, whyh, by, out);
  finals<<<512, 256, 0, stream>>>(h0buf, h1buf, out);
}